// Round 1
// baseline (422.784 us; speedup 1.0000x reference)
//
#include <hip/hip_runtime.h>

// SparseConv2d N=32, OC=IC=256, H=W=56, K=3, pad=1 -> dense bf16 MFMA implicit GEMM
// V2: double-buffered LDS + async-split staging (issue loads early, cvt+ds_write late),
//     one __syncthreads per ic-chunk. Attacks the 65% MFMA-idle time seen at
//     MfmaUtil=20%/VALUBusy=11%/Occ=19% (latency-bound, 2 waves/SIMD).
constexpr int NB=32, ICC=256, OCC=256, HH=56, WW=56;
constexpr int HW=HH*WW, CHW=ICC*HW;
constexpr int YT=14, MT=2;
constexpr int LROW=58;           // 56 cols + 2 halo
constexpr int PAD=36;            // ic slots per (r,c): 32 data + 4 pad (72B stride -> spread banks)
constexpr int LDS_ELEMS=6*LROW*PAD;   // 12528 ushort = 25056 B per buffer
constexpr int BUF_BYTES=LDS_ELEMS*2;  // byte size of one buffer

using short8  = __attribute__((ext_vector_type(8))) short;   // 8 x bf16 bits (A/B frag)
using short4v = __attribute__((ext_vector_type(4))) short;
using f32x4   = __attribute__((ext_vector_type(4))) float;   // C/D frag

__device__ inline unsigned bf16rne(float x){
  unsigned u = __float_as_uint(x);
  return (u + 0x7fffu + ((u>>16)&1u)) >> 16;   // round-to-nearest-even
}

// wb[j][oc][ic] bf16, j = kh*3+kw, masked weights. 1.18 MB in d_ws.
__global__ __launch_bounds__(256) void pack_weights(
    const float* __restrict__ w, const int* __restrict__ mask,
    unsigned short* __restrict__ wb){
  const int oc = blockIdx.x, ic = threadIdx.x;
  const int base = (oc*ICC + ic)*9;
  #pragma unroll
  for (int j=0;j<9;++j){
    float v = (mask[base+j] != 0) ? w[base+j] : 0.f;
    wb[(j*OCC + oc)*ICC + ic] = (unsigned short)bf16rne(v);
  }
}

__global__ __launch_bounds__(256,2) void conv_mfma(
    const float* __restrict__ in, const unsigned short* __restrict__ wb,
    const float* __restrict__ bias, float* __restrict__ out){
  __shared__ unsigned short xt[2*LDS_ELEMS];   // 2 x [6 rows][58 cols][36 ic-slots] = 50112 B

  // XCD-aware decode: lid&7 = XCD residue -> each XCD sees only 4 of 32 batches
  const int lid  = blockIdx.x;
  const int xcd  = lid & 7, slot = lid >> 3;          // 112 slots per residue
  const int ngrp = slot / 28, rem = slot - ngrp*28;   // same-n blocks adjacent
  const int mt   = rem / 14,  yt  = rem - mt*14;
  const int n    = xcd + 8*ngrp;
  const int y0   = yt*4, ocb = mt*128;

  const int tid  = threadIdx.x;
  const int lane = tid & 63, wv = tid >> 6;
  const int q    = lane >> 4, l16 = lane & 15;

  // zero BOTH buffers once: halo cells (c=0, c=57, skipped rows) stay zero for all chunks
  for (int i = tid; i < LDS_ELEMS; i += 256) ((unsigned*)xt)[i] = 0u;

  // wave tile: 64 ocs x 112 px (4 x 7 MFMA tiles of 16x16)
  const int ocw = ocb + (wv & 1)*64;
  const int pxw = (wv >> 1)*112;

  int pbase[7];
  #pragma unroll
  for (int p=0;p<7;++p){
    int px = pxw + p*16 + l16;          // pixel within 4x56 tile (row-crossing OK)
    int yl = px / 56, x = px - yl*56;
    pbase[p] = (yl*LROW + x)*(PAD*2) + q*16;   // LDS byte addr within a buffer
  }

  f32x4 acc[4][7];
  #pragma unroll
  for (int s=0;s<4;++s)
    #pragma unroll
    for (int p=0;p<7;++p) acc[s][p] = (f32x4){0.f,0.f,0.f,0.f};

  const int rskipA = (yt==0)      ? 0 : -1;   // input row y0-1 invalid
  const int rskipB = (yt==YT-1)   ? 5 : -1;   // input row y0+4 invalid

  // held staging registers: 6 items x 2 float4 = 48 VGPR, live across compute
  float4 g0v[6], g1v[6];

  // ---- issue the 12 global loads for chunk ch (items: r(6) x xg(14) x icp(16)) ----
  auto stage_load = [&](int ch){
    const int ic0 = ch*32;
    #pragma unroll
    for (int i=0;i<6;++i){
      int idx = tid + i*256;
      if (idx < 1344){
        int r  = idx / 224;
        int r2 = idx - r*224;
        int xg = r2 >> 4, icp = r2 & 15;
        if (r != rskipA && r != rskipB){
          int y = y0 - 1 + r;
          const float* gp = in + n*CHW + (ic0 + icp*2)*HW + y*WW + xg*4;
          g0v[i] = *(const float4*)gp;          // ic plane
          g1v[i] = *(const float4*)(gp + HW);   // ic+1 plane
        }
      }
    }
  };

  // ---- convert + write held registers into buffer `buf` (conflict-free ds_write_b32) ----
  auto stage_write = [&](int buf){
    unsigned* base = (unsigned*)xt + buf*(LDS_ELEMS/2);
    #pragma unroll
    for (int i=0;i<6;++i){
      int idx = tid + i*256;
      if (idx < 1344){
        int r  = idx / 224;
        int r2 = idx - r*224;
        int xg = r2 >> 4, icp = r2 & 15;
        if (r != rskipA && r != rskipB){
          float4 g0 = g0v[i], g1 = g1v[i];
          unsigned w0 = bf16rne(g0.x) | (bf16rne(g1.x)<<16);
          unsigned w1 = bf16rne(g0.y) | (bf16rne(g1.y)<<16);
          unsigned w2 = bf16rne(g0.z) | (bf16rne(g1.z)<<16);
          unsigned w3 = bf16rne(g0.w) | (bf16rne(g1.w)<<16);
          unsigned* dp = base + (r*LROW + 1 + xg*4)*(PAD/2) + icp;
          dp[0]         = w0;            // col c=1+xg*4 .. +3, ic pair contiguous
          dp[PAD/2]     = w1;
          dp[PAD]       = w2;
          dp[3*(PAD/2)] = w3;
        }
      }
    }
  };

  // ---- K-slice MFMA over buffer `buf`: 9 offsets x 32 ics ----
  auto compute = [&](int buf, int ch){
    const int ic0 = ch*32;
    const char* xb = (const char*)xt + buf*BUF_BYTES;
    #pragma unroll
    for (int kh=0;kh<3;++kh){
      #pragma unroll
      for (int kw=0;kw<3;++kw){
        const int j = kh*3 + kw;
        // A-frags: one contiguous 16B global load per oc-subtile (L2-resident wb)
        const unsigned short* wp = wb + (j*OCC + ocw + l16)*ICC + ic0 + q*8;
        short8 a0 = *(const short8*)(wp          );
        short8 a1 = *(const short8*)(wp + 16*ICC );
        short8 a2 = *(const short8*)(wp + 32*ICC );
        short8 a3 = *(const short8*)(wp + 48*ICC );
        const int doff = (kh*LROW + kw)*(PAD*2);   // shift within LDS tile
        #pragma unroll
        for (int p=0;p<7;++p){
          const char* bp = xb + pbase[p] + doff;
          short4v blo = *(const short4v*)(bp    );   // ds_read_b64, 8B aligned
          short4v bhi = *(const short4v*)(bp + 8);
          short8 b = __builtin_shufflevector(blo, bhi, 0,1,2,3,4,5,6,7);
          acc[0][p] = __builtin_amdgcn_mfma_f32_16x16x32_bf16(a0, b, acc[0][p], 0,0,0);
          acc[1][p] = __builtin_amdgcn_mfma_f32_16x16x32_bf16(a1, b, acc[1][p], 0,0,0);
          acc[2][p] = __builtin_amdgcn_mfma_f32_16x16x32_bf16(a2, b, acc[2][p], 0,0,0);
          acc[3][p] = __builtin_amdgcn_mfma_f32_16x16x32_bf16(a3, b, acc[3][p], 0,0,0);
        }
      }
    }
  };

  // prologue: loads for chunk 0 in flight while zeroing finishes
  stage_load(0);
  __syncthreads();          // zeroing complete before first staging write
  stage_write(0);
  __syncthreads();          // buf0 ready

  // main loop: compute buf[cur] while chunk ch+1's loads are in flight;
  // cvt+ds_write into buf[cur^1] after compute; ONE barrier per chunk.
  int cur = 0;
  #pragma unroll 2
  for (int ch=0; ch<8; ++ch){
    if (ch < 7) stage_load(ch+1);     // issue early: HBM latency hides under MFMA
    compute(cur, ch);
    if (ch < 7) stage_write(cur^1);   // write other buffer: no conflict with readers of cur
    __syncthreads();
    cur ^= 1;
  }

  // ---- epilogue: D row = oc (quad*4+reg), col = px (lane&15)  [m89 layout] ----
  #pragma unroll
  for (int s=0;s<4;++s){
    const int oc4 = ocw + s*16 + q*4;
    float4 bv = *(const float4*)(bias + oc4);
    #pragma unroll
    for (int i=0;i<4;++i){
      const float bb = (i==0)?bv.x:(i==1)?bv.y:(i==2)?bv.z:bv.w;
      float* op = out + (n*OCC + oc4 + i)*HW + y0*WW + pxw + l16;
      #pragma unroll
      for (int p=0;p<7;++p){
        op[p*16] = acc[s][p][i] + bb;
      }
    }
  }
}

extern "C" void kernel_launch(void* const* d_in, const int* in_sizes, int n_in,
                              void* d_out, int out_size, void* d_ws, size_t ws_size,
                              hipStream_t stream) {
  const float* in   = (const float*)d_in[0];
  const float* w    = (const float*)d_in[1];
  const float* bias = (const float*)d_in[2];
  const int*   mask = (const int*)d_in[3];
  float*       out  = (float*)d_out;
  unsigned short* wb = (unsigned short*)d_ws;   // 9*256*256*2 B = 1.18 MB

  pack_weights<<<OCC, 256, 0, stream>>>(w, mask, wb);
  conv_mfma<<<8*4*MT*YT, 256, 0, stream>>>(in, wb, bias, out);  // 896 blocks
}

// Round 2
// 345.790 us; speedup vs baseline: 1.2227x; 1.2227x over previous
//
#include <hip/hip_runtime.h>

// SparseConv2d N=32, OC=IC=256, H=W=56, K=3, pad=1 -> dense bf16 MFMA implicit GEMM
// V3: pre-pack input to bf16 channels-last (inb[n][y][x][ic]) so conv staging is pure
//     global_load_lds (no VGPR round-trip, no cvt VALU, nothing to spill). m97 schedule:
//     prefetch ch+1 into buf^1 before compute(ch), ONE barrier per chunk.
//     ic-group XOR swizzle folded into the GLOBAL source address (m173) so the
//     B ds_read_b128 is bank-spread; halo handled at read time via cndmask to a zero slab.
constexpr int NB=32, ICC=256, OCC=256, HH=56, WW=56;
constexpr int HW=HH*WW, CHW=ICC*HW;
constexpr int YT=14, MT=2;
constexpr int BUFB = 6*56*64;          // bytes per LDS buffer: [6 rows][56 cols][32 ic]*2B
constexpr int ZOFF = 2*BUFB;           // 16B zero slab after both buffers
// ---- legacy fp32 path constants (fallback if ws too small) ----
constexpr int LROW=58;
constexpr int PAD=36;
constexpr int LDS_ELEMS=6*LROW*PAD;

using short8  = __attribute__((ext_vector_type(8))) short;   // 8 x bf16 bits (A/B frag)
using short4v = __attribute__((ext_vector_type(4))) short;
using f32x4   = __attribute__((ext_vector_type(4))) float;   // C/D frag

__device__ inline unsigned bf16rne(float x){
  unsigned u = __float_as_uint(x);
  return (u + 0x7fffu + ((u>>16)&1u)) >> 16;   // round-to-nearest-even
}

// wb[j][oc][ic] bf16, j = kh*3+kw, masked weights. 1.18 MB in d_ws.
__global__ __launch_bounds__(256) void pack_weights(
    const float* __restrict__ w, const int* __restrict__ mask,
    unsigned short* __restrict__ wb){
  const int oc = blockIdx.x, ic = threadIdx.x;
  const int base = (oc*ICC + ic)*9;
  #pragma unroll
  for (int j=0;j<9;++j){
    float v = (mask[base+j] != 0) ? w[base+j] : 0.f;
    wb[(j*OCC + oc)*ICC + ic] = (unsigned short)bf16rne(v);
  }
}

// in[n][ic][y][x] fp32 -> inb[n][y][x][ic] bf16 (channels-last). One block per (n,y) row.
__global__ __launch_bounds__(256) void pack_input(
    const float* __restrict__ in, unsigned short* __restrict__ inb){
  __shared__ unsigned short t[56*258];       // [x][258] (+2 pad: conflict-free transpose)
  const int bid = blockIdx.x;
  const int n = bid/56, y = bid - n*56;
  const float* src = in + (size_t)n*CHW + y*WW;
  const int tid = threadIdx.x;
  #pragma unroll
  for (int i=0;i<14;++i){                    // 3584 float4 items: (ic, xg)
    int idx = tid + i*256;
    int ic = idx / 14, xg = idx - ic*14;
    float4 v = *(const float4*)(src + ic*HW + xg*4);
    int xb = xg*4;
    t[(xb+0)*258 + ic] = (unsigned short)bf16rne(v.x);
    t[(xb+1)*258 + ic] = (unsigned short)bf16rne(v.y);
    t[(xb+2)*258 + ic] = (unsigned short)bf16rne(v.z);
    t[(xb+3)*258 + ic] = (unsigned short)bf16rne(v.w);
  }
  __syncthreads();
  unsigned* dst = (unsigned*)(inb + (size_t)(n*56+y)*56*256);
  #pragma unroll
  for (int i=0;i<28;++i){                    // 7168 u32, fully coalesced out
    int idx = tid + i*256;
    int x = idx >> 7, icp = idx & 127;
    dst[idx] = *(const unsigned*)&t[x*258 + icp*2];
  }
}

__global__ __launch_bounds__(256,2) void conv_mfma(
    const unsigned short* __restrict__ inb, const unsigned short* __restrict__ wb,
    const float* __restrict__ bias, float* __restrict__ out){
  __shared__ unsigned short xt[(2*BUFB + 16)/2];   // 2 buffers + 16B zero slab = 43 KB

  // XCD-aware decode: lid&7 = XCD residue -> each XCD sees only 4 of 32 batches
  const int lid  = blockIdx.x;
  const int xcd  = lid & 7, slot = lid >> 3;
  const int ngrp = slot / 28, rem = slot - ngrp*28;
  const int mt   = rem / 14,  yt  = rem - mt*14;
  const int n    = xcd + 8*ngrp;
  const int y0   = yt*4, ocb = mt*128;

  const int tid  = threadIdx.x;
  const int lane = tid & 63, wv = tid >> 6;
  const int q    = lane >> 4, l16 = lane & 15;

  // wave tile: 64 ocs x 112 px (4 x 7 MFMA tiles of 16x16)
  const int ocw = ocb + (wv & 1)*64;
  const int pxw = (wv >> 1)*112;

  int xp[7], yl[7];
  #pragma unroll
  for (int p=0;p<7;++p){
    int px = pxw + p*16 + l16;          // pixel within 4x56 tile (row-crossing OK)
    yl[p] = px / 56;  xp[p] = px - yl[p]*56;
  }

  f32x4 acc[4][7];
  #pragma unroll
  for (int s=0;s<4;++s)
    #pragma unroll
    for (int p=0;p<7;++p) acc[s][p] = (f32x4){0.f,0.f,0.f,0.f};

  if (tid == 0) *(f32x4*)((char*)xt + ZOFF) = (f32x4){0.f,0.f,0.f,0.f};  // zero slab

  const unsigned short* nb = inb + (size_t)n*(56*56*256);

  // ---- stage chunk ch into buffer buf: 1344 x 16B global_load_lds, LDS linear ----
  // item idx -> (r = idx/224, cc = (idx%224)>>2, sub = idx&3); LDS addr = idx*16 (lane-linear).
  // ic-group swizzle in the GLOBAL address: icg = sub ^ ((cc>>1)&3). Rows clamped (read masks).
  auto stage = [&](int buf, int ch){
    const int ic0 = ch*32;
    #pragma unroll
    for (int i=0;i<6;++i){
      int idx = tid + i*256;
      if (idx < 1344){                       // wave-uniform guard (i==5 -> tid<64)
        int r   = idx / 224;
        int rm  = idx - r*224;
        int cc  = rm >> 2, sub = rm & 3;
        int y   = y0 - 1 + r;
        y = y < 0 ? 0 : (y > 55 ? 55 : y);   // clamp; invalid rows masked at read time
        int icg = sub ^ ((cc>>1)&3);
        const unsigned short* gp = nb + (y*56 + cc)*256 + ic0 + icg*8;
        char* lp = (char*)xt + buf*BUFB + idx*16;
        __builtin_amdgcn_global_load_lds(
            (const __attribute__((address_space(1))) void*)gp,
            (__attribute__((address_space(3))) void*)lp, 16, 0, 0);
      }
    }
  };

  // ---- K-slice MFMA over buffer buf: 9 offsets x 32 ics ----
  auto compute = [&](int buf, int ch){
    const int ic0 = ch*32;
    const char* xb = (const char*)xt + buf*BUFB;
    const char* zp = (const char*)xt + ZOFF;
    #pragma unroll
    for (int kh=0;kh<3;++kh){
      #pragma unroll
      for (int kw=0;kw<3;++kw){
        const int j = kh*3 + kw;
        const unsigned short* wp = wb + (j*OCC + ocw + l16)*ICC + ic0 + q*8;
        short8 a0 = *(const short8*)(wp          );
        short8 a1 = *(const short8*)(wp + 16*ICC );
        short8 a2 = *(const short8*)(wp + 32*ICC );
        short8 a3 = *(const short8*)(wp + 48*ICC );
        #pragma unroll
        for (int p=0;p<7;++p){
          int xq = xp[p] + kw - 1;                       // input col
          int yq = y0 - 1 + yl[p] + kh;                  // input row
          bool valid = ((unsigned)xq < 56u) & ((unsigned)yq < 56u);
          int addr = (((yl[p]+kh)*56 + xq)<<6) + ((q ^ ((xq>>1)&3))<<4);
          const char* bp = valid ? (xb + addr) : zp;     // cndmask on address
          short8 b = *(const short8*)bp;                 // ds_read_b128
          acc[0][p] = __builtin_amdgcn_mfma_f32_16x16x32_bf16(a0, b, acc[0][p], 0,0,0);
          acc[1][p] = __builtin_amdgcn_mfma_f32_16x16x32_bf16(a1, b, acc[1][p], 0,0,0);
          acc[2][p] = __builtin_amdgcn_mfma_f32_16x16x32_bf16(a2, b, acc[2][p], 0,0,0);
          acc[3][p] = __builtin_amdgcn_mfma_f32_16x16x32_bf16(a3, b, acc[3][p], 0,0,0);
        }
      }
    }
  };

  // prologue: stage chunk 0 into buf 0, drain, barrier
  stage(0, 0);
  __syncthreads();                    // drains vmcnt -> buf0 ready, slab zeroed

  // main loop: prefetch ch+1 fire-and-forget, compute ch, one barrier per chunk.
  for (int ch=0; ch<8; ++ch){
    if (ch < 7) stage((ch+1)&1, ch+1);
    compute(ch&1, ch);
    __syncthreads();                  // drains prefetch vmcnt + guards buf reuse
  }

  // ---- epilogue: D row = oc (quad*4+reg), col = px (lane&15)  [m89 layout] ----
  #pragma unroll
  for (int s=0;s<4;++s){
    const int oc4 = ocw + s*16 + q*4;
    float4 bv = *(const float4*)(bias + oc4);
    #pragma unroll
    for (int i=0;i<4;++i){
      const float bb = (i==0)?bv.x:(i==1)?bv.y:(i==2)?bv.z:bv.w;
      float* op = out + (n*OCC + oc4 + i)*HW + y0*WW + pxw + l16;
      #pragma unroll
      for (int p=0;p<7;++p){
        op[p*16] = acc[s][p][i] + bb;
      }
    }
  }
}

// ---------------- fallback: V1 fp32-staging path (ws too small) ----------------
__global__ __launch_bounds__(256,2) void conv_mfma_f32(
    const float* __restrict__ in, const unsigned short* __restrict__ wb,
    const float* __restrict__ bias, float* __restrict__ out){
  __shared__ unsigned short xt[LDS_ELEMS];

  const int lid  = blockIdx.x;
  const int xcd  = lid & 7, slot = lid >> 3;
  const int ngrp = slot / 28, rem = slot - ngrp*28;
  const int mt   = rem / 14,  yt  = rem - mt*14;
  const int n    = xcd + 8*ngrp;
  const int y0   = yt*4, ocb = mt*128;

  const int tid  = threadIdx.x;
  const int lane = tid & 63, wv = tid >> 6;
  const int q    = lane >> 4, l16 = lane & 15;

  for (int i = tid; i < LDS_ELEMS/2; i += 256) ((unsigned*)xt)[i] = 0u;

  const int ocw = ocb + (wv & 1)*64;
  const int pxw = (wv >> 1)*112;

  int pbase[7];
  #pragma unroll
  for (int p=0;p<7;++p){
    int px = pxw + p*16 + l16;
    int ylv = px / 56, x = px - ylv*56;
    pbase[p] = (ylv*LROW + x)*(PAD*2) + q*16;
  }

  f32x4 acc[4][7];
  #pragma unroll
  for (int s=0;s<4;++s)
    #pragma unroll
    for (int p=0;p<7;++p) acc[s][p] = (f32x4){0.f,0.f,0.f,0.f};

  const int rskipA = (yt==0)      ? 0 : -1;
  const int rskipB = (yt==YT-1)   ? 5 : -1;

  __syncthreads();

  for (int ch=0; ch<8; ++ch){
    const int ic0 = ch*32;
    #pragma unroll
    for (int i=0;i<6;++i){
      int idx = tid + i*256;
      if (idx < 1344){
        int r  = idx / 224;
        int r2 = idx - r*224;
        int xg = r2 >> 4, icp = r2 & 15;
        if (r != rskipA && r != rskipB){
          int y = y0 - 1 + r;
          const float* gp = in + n*CHW + (ic0 + icp*2)*HW + y*WW + xg*4;
          float4 g0 = *(const float4*)gp;
          float4 g1 = *(const float4*)(gp + HW);
          unsigned w0 = bf16rne(g0.x) | (bf16rne(g1.x)<<16);
          unsigned w1 = bf16rne(g0.y) | (bf16rne(g1.y)<<16);
          unsigned w2 = bf16rne(g0.z) | (bf16rne(g1.z)<<16);
          unsigned w3 = bf16rne(g0.w) | (bf16rne(g1.w)<<16);
          unsigned* dp = (unsigned*)xt + (r*LROW + 1 + xg*4)*(PAD/2) + icp;
          dp[0]         = w0;
          dp[PAD/2]     = w1;
          dp[PAD]       = w2;
          dp[3*(PAD/2)] = w3;
        }
      }
    }
    __syncthreads();

    #pragma unroll
    for (int kh=0;kh<3;++kh){
      #pragma unroll
      for (int kw=0;kw<3;++kw){
        const int j = kh*3 + kw;
        const unsigned short* wp = wb + (j*OCC + ocw + l16)*ICC + ic0 + q*8;
        short8 a0 = *(const short8*)(wp          );
        short8 a1 = *(const short8*)(wp + 16*ICC );
        short8 a2 = *(const short8*)(wp + 32*ICC );
        short8 a3 = *(const short8*)(wp + 48*ICC );
        const int doff = (kh*LROW + kw)*(PAD*2);
        #pragma unroll
        for (int p=0;p<7;++p){
          const char* bp = (const char*)xt + pbase[p] + doff;
          short4v blo = *(const short4v*)(bp    );
          short4v bhi = *(const short4v*)(bp + 8);
          short8 b = __builtin_shufflevector(blo, bhi, 0,1,2,3,4,5,6,7);
          acc[0][p] = __builtin_amdgcn_mfma_f32_16x16x32_bf16(a0, b, acc[0][p], 0,0,0);
          acc[1][p] = __builtin_amdgcn_mfma_f32_16x16x32_bf16(a1, b, acc[1][p], 0,0,0);
          acc[2][p] = __builtin_amdgcn_mfma_f32_16x16x32_bf16(a2, b, acc[2][p], 0,0,0);
          acc[3][p] = __builtin_amdgcn_mfma_f32_16x16x32_bf16(a3, b, acc[3][p], 0,0,0);
        }
      }
    }
    __syncthreads();
  }

  #pragma unroll
  for (int s=0;s<4;++s){
    const int oc4 = ocw + s*16 + q*4;
    float4 bv = *(const float4*)(bias + oc4);
    #pragma unroll
    for (int i=0;i<4;++i){
      const float bb = (i==0)?bv.x:(i==1)?bv.y:(i==2)?bv.z:bv.w;
      float* op = out + (n*OCC + oc4 + i)*HW + y0*WW + pxw + l16;
      #pragma unroll
      for (int p=0;p<7;++p){
        op[p*16] = acc[s][p][i] + bb;
      }
    }
  }
}

extern "C" void kernel_launch(void* const* d_in, const int* in_sizes, int n_in,
                              void* d_out, int out_size, void* d_ws, size_t ws_size,
                              hipStream_t stream) {
  const float* in   = (const float*)d_in[0];
  const float* w    = (const float*)d_in[1];
  const float* bias = (const float*)d_in[2];
  const int*   mask = (const int*)d_in[3];
  float*       out  = (float*)d_out;
  unsigned short* wb = (unsigned short*)d_ws;        // 9*256*256*2 B = 1.18 MB

  const size_t WB_BYTES  = (size_t)9*OCC*ICC*2;      // 1179648 (256B aligned)
  const size_t INB_BYTES = (size_t)NB*HH*WW*ICC*2;   // 51.4 MB

  pack_weights<<<OCC, 256, 0, stream>>>(w, mask, wb);
  if (ws_size >= WB_BYTES + INB_BYTES){
    unsigned short* inb = (unsigned short*)((char*)d_ws + WB_BYTES);
    pack_input<<<NB*HH, 256, 0, stream>>>(in, inb);                  // 1792 blocks
    conv_mfma<<<8*4*MT*YT, 256, 0, stream>>>(inb, wb, bias, out);    // 896 blocks
  } else {
    conv_mfma_f32<<<8*4*MT*YT, 256, 0, stream>>>(in, wb, bias, out); // proven V1 path
  }
}